// Round 10
// baseline (280.192 us; speedup 1.0000x reference)
//
#include <hip/hip_runtime.h>
#include <hip/hip_bf16.h>

// Problem constants (fixed by setup_inputs)
#define B_    16
#define N1    1024
#define NP    4096
#define D1c   256
#define D2c   128
#define DH    256
#define NQ    (B_*NP)        // 65536 rows
#define KD1   (D1c+D2c)      // 384

// Workspace layout (bytes).
#define X_OFF      0ul                     // x bf16: 65536*384*2
#define Y1_OFF     50331648ul              // y1 / y2 bf16: 65536*256*2
#define SCALE1_OFF 85458944ul
#define SHIFT1_OFF (SCALE1_OFF+1024ul)
#define SCALE2_OFF (SCALE1_OFF+2048ul)
#define SHIFT2_OFF (SCALE1_OFF+3072ul)
#define W1B_OFF    85467136ul              // bf16 W1: 256*384*2
#define W2B_OFF    85663744ul              // bf16 W2: 256*256*2
#define PS_OFF     85794816ul              // float Psum[1024][256] = 1 MB
#define PQ_OFF     86843392ul              // float Psq [1024][256] = 1 MB

using short8  = __attribute__((ext_vector_type(8))) short;
using floatx4 = __attribute__((ext_vector_type(4))) float;
using f4v     = __attribute__((ext_vector_type(4))) float;
using f2v     = __attribute__((ext_vector_type(2))) float;
typedef const __attribute__((address_space(1))) unsigned int* gas_t;
typedef __attribute__((address_space(3))) unsigned int* las_t;
typedef const __attribute__((address_space(4))) float* c4f_t;   // constant AS -> s_load
typedef const __attribute__((address_space(4))) f4v*   c4v_t;

// bf16 RNE cast (bit-level, matches np/jax round-to-nearest-even; inputs finite)
static __device__ __forceinline__ unsigned short f2b(float f) {
    unsigned int u = __builtin_bit_cast(unsigned int, f);
    return (unsigned short)((u + 0x7FFFu + ((u >> 16) & 1u)) >> 16);
}
static __device__ __forceinline__ float b2f(unsigned short u) {
    unsigned int x = ((unsigned int)u) << 16;
    return __builtin_bit_cast(float, x);
}

// ---------------- fused kNN + interp/concat (+ weight cvt on spare blocks) ----
// (unchanged from R6: XCD-affinity remap, scalar candidate loads, packed
// distances, min/med3 selection, exact top_k tie semantics)
__global__ __launch_bounds__(256) void knn_interp_kernel(
    const float* __restrict__ xyz1, const float* __restrict__ xyz2,
    const float* __restrict__ f1,   const float* __restrict__ feat2,
    const float* __restrict__ W1,   const float* __restrict__ W2,
    unsigned short* __restrict__ W1b, unsigned short* __restrict__ W2b,
    unsigned short* __restrict__ x)
{
#pragma clang fp contract(off)
    const int tid = threadIdx.x;
    if (blockIdx.x >= 1024) {            // ---- weight conversion blocks ----
        int i = (blockIdx.x - 1024) * 256 + tid;
        if (i < DH * KD1) W1b[i] = f2b(W1[i]);
        else              W2b[i - DH * KD1] = f2b(W2[i - DH * KD1]);
        return;
    }

    __shared__ float pd[12 * 64];
    __shared__ int   pi[12 * 64];
    __shared__ int   sidx[64 * 3];
    __shared__ float swt [64 * 3];

    const int xcd  = blockIdx.x & 7;
    const int slot = blockIdx.x >> 3;          // 0..127
    const int batch = xcd * 2 + (slot >> 6);
    const int qblk  = slot & 63;

    const int ql  = tid & 63;
    const int seg = tid >> 6;
    const int seg_u = __builtin_amdgcn_readfirstlane(seg);
    const int n = batch * NP + qblk * 64 + ql;
    const float* qp = xyz2 + (size_t)n * 3;
    const float qx = qp[0], qy = qp[1], qz = qp[2];
    const f2v qx2 = {qx, qx}, qy2 = {qy, qy}, qz2 = {qz, qz};

    c4f_t cp = (c4f_t)(const void*)(xyz1 + (size_t)batch * (N1 * 3))
               + (size_t)seg_u * 768;

    float d0 = 3.4e38f, d1v = 3.4e38f, d2v = 3.4e38f;
    int   i0 = 0, i1 = 0, i2 = 0;

#define SEL(jj, dd) do {                                                      \
        bool c0 = (dd) < d0, c1 = (dd) < d1v, c2 = (dd) < d2v;                \
        i2 = c2 ? (c1 ? i1 : (jj)) : i2;                                      \
        i1 = c1 ? (c0 ? i0 : (jj)) : i1;                                      \
        i0 = c0 ? (jj) : i0;                                                  \
        d2v = __builtin_amdgcn_fmed3f(d1v, d2v, (dd));                        \
        d1v = __builtin_amdgcn_fmed3f(d0, d1v, (dd));                         \
        d0  = fminf(d0, (dd));                                                \
    } while (0)

    const int jbase = seg_u * 256;
    for (int j = 0; j < 256; j += 4) {
        f4v p0 = *(c4v_t)(cp + j * 3);
        f4v p1 = *(c4v_t)(cp + j * 3 + 4);
        f4v p2 = *(c4v_t)(cp + j * 3 + 8);
        {
            f2v cx2 = {p0.x, p0.w}, cy2 = {p0.y, p1.x}, cz2 = {p0.z, p1.y};
            f2v dx2 = qx2 - cx2, dy2 = qy2 - cy2, dz2 = qz2 - cz2;
            f2v dd2 = (dx2 * dx2 + dy2 * dy2) + dz2 * dz2;
            SEL(jbase + j + 0, dd2.x);
            SEL(jbase + j + 1, dd2.y);
        }
        {
            f2v cx2 = {p1.z, p2.y}, cy2 = {p1.w, p2.z}, cz2 = {p2.x, p2.w};
            f2v dx2 = qx2 - cx2, dy2 = qy2 - cy2, dz2 = qz2 - cz2;
            f2v dd2 = (dx2 * dx2 + dy2 * dy2) + dz2 * dz2;
            SEL(jbase + j + 2, dd2.x);
            SEL(jbase + j + 3, dd2.y);
        }
    }
#undef SEL

    pd[(seg * 3 + 0) * 64 + ql] = d0;   pi[(seg * 3 + 0) * 64 + ql] = i0;
    pd[(seg * 3 + 1) * 64 + ql] = d1v;  pi[(seg * 3 + 1) * 64 + ql] = i1;
    pd[(seg * 3 + 2) * 64 + ql] = d2v;  pi[(seg * 3 + 2) * 64 + ql] = i2;
    __syncthreads();

    if (tid < 64) {
        float e0 = pd[0 * 64 + tid], e1 = pd[1 * 64 + tid], e2 = pd[2 * 64 + tid];
        int   j0 = pi[0 * 64 + tid], j1 = pi[1 * 64 + tid], j2 = pi[2 * 64 + tid];
#pragma unroll
        for (int s = 3; s < 12; s++) {
            float d = pd[s * 64 + tid];
            int   i = pi[s * 64 + tid];
            bool c2 = d < e2;
            e2 = c2 ? d : e2;  j2 = c2 ? i : j2;
            bool c1 = e2 < e1;
            float tf = e1; e1 = c1 ? e2 : e1; e2 = c1 ? tf : e2;
            int   ti = j1; j1 = c1 ? j2 : j1; j2 = c1 ? ti : j2;
            bool c0 = e1 < e0;
            tf = e0; e0 = c0 ? e1 : e0; e1 = c0 ? tf : e1;
            ti = j0; j0 = c0 ? j1 : j0; j1 = c0 ? ti : j1;
        }
        const float eps = 1.1920929e-07f;
        float v0 = 1.0f / __fadd_rn(e0, eps);
        float v1 = 1.0f / __fadd_rn(e1, eps);
        float v2 = 1.0f / __fadd_rn(e2, eps);
        float s  = __fadd_rn(__fadd_rn(v0, v1), v2);
        sidx[tid * 3 + 0] = j0;  swt[tid * 3 + 0] = v0 / s;
        sidx[tid * 3 + 1] = j1;  swt[tid * 3 + 1] = v1 / s;
        sidx[tid * 3 + 2] = j2;  swt[tid * 3 + 2] = v2 / s;
    }
    __syncthreads();

    const int lane = tid & 63, wv = tid >> 6;
    const float* fb = f1 + (size_t)batch * (N1 * D1c);
#pragma unroll 4
    for (int it = 0; it < 16; it++) {
        const int q  = wv * 16 + it;
        const int nr = batch * NP + qblk * 64 + q;
        const int a0 = sidx[q * 3 + 0], a1 = sidx[q * 3 + 1], a2 = sidx[q * 3 + 2];
        const float w0 = swt[q * 3 + 0], w1 = swt[q * 3 + 1], w2 = swt[q * 3 + 2];
        float4 a = *(const float4*)(fb + (size_t)a0 * D1c + lane * 4);
        float4 b = *(const float4*)(fb + (size_t)a1 * D1c + lane * 4);
        float4 c = *(const float4*)(fb + (size_t)a2 * D1c + lane * 4);
        ushort4 o;
        o.x = f2b(__fadd_rn(__fadd_rn(__fmul_rn(a.x,w0), __fmul_rn(b.x,w1)), __fmul_rn(c.x,w2)));
        o.y = f2b(__fadd_rn(__fadd_rn(__fmul_rn(a.y,w0), __fmul_rn(b.y,w1)), __fmul_rn(c.y,w2)));
        o.z = f2b(__fadd_rn(__fadd_rn(__fmul_rn(a.z,w0), __fmul_rn(b.z,w1)), __fmul_rn(c.z,w2)));
        o.w = f2b(__fadd_rn(__fadd_rn(__fmul_rn(a.w,w0), __fmul_rn(b.w,w1)), __fmul_rn(c.w,w2)));
        *(ushort4*)(x + (size_t)nr * KD1 + lane * 4) = o;
        float2 f = *(const float2*)(feat2 + (size_t)nr * D2c + lane * 2);
        ushort2 o2; o2.x = f2b(f.x); o2.y = f2b(f.y);
        *(ushort2*)(x + (size_t)nr * KD1 + D1c + lane * 2) = o2;
    }
}

// ---------------- shared gemm epilogue: stats + 4-pass LDS-transpose store ----
// smem: 8192 shorts (16 KB). Rows handled 32 at a time.
static __device__ __forceinline__ void gemm_epilogue(
    short* smem, floatx4 (&acc)[4][4], const float* __restrict__ bias,
    unsigned short* __restrict__ Out, float* __restrict__ Psum, float* __restrict__ Psq,
    long m0, int tid, int wm, int wn, int quad, int l16, int pslot)
{
    // bias + per-column partial sum/sumsq
#pragma unroll
    for (int nb = 0; nb < 4; nb++) {
        const int col = wn * 64 + nb * 16 + l16;
        const float bia = bias[col];
        float s = 0.f, q = 0.f;
#pragma unroll
        for (int mb = 0; mb < 4; mb++)
#pragma unroll
            for (int r = 0; r < 4; r++) {
                float v = acc[mb][nb][r] + bia;
                acc[mb][nb][r] = v;
                s += v; q += v * v;
            }
        s += __shfl_xor(s, 16); s += __shfl_xor(s, 32);
        q += __shfl_xor(q, 16); q += __shfl_xor(q, 32);
        if (quad == 0) {
            Psum[pslot * 256 + col] = s;
            Psq [pslot * 256 + col] = q;
        }
    }

    // 4 passes of 32 rows through 16 KB LDS, contiguous 16 B stores
#pragma unroll
    for (int p = 0; p < 4; p++) {
        __syncthreads();
        if (wm == (p >> 1)) {
#pragma unroll
            for (int mb2 = 0; mb2 < 2; mb2++) {
                const int mb = (p & 1) * 2 + mb2;
#pragma unroll
                for (int r = 0; r < 4; r++) {
                    const int rloc = mb2 * 16 + quad * 4 + r;
#pragma unroll
                    for (int nb = 0; nb < 4; nb++) {
                        const int col = wn * 64 + nb * 16 + l16;
                        smem[rloc * 256 + ((((col >> 3) + rloc) & 31) << 3) + (col & 7)] =
                            (short)f2b(acc[mb][nb][r]);
                    }
                }
            }
        }
        __syncthreads();
#pragma unroll
        for (int h = 0; h < 2; h++) {
            const int idx = h * 512 + tid;
            const int rloc = idx >> 5, cg = idx & 31;
            const int col0 = ((cg - rloc + 32) & 31) << 3;
            short8 v = *(const short8*)(smem + rloc * 256 + cg * 8);
            *(short8*)(Out + (size_t)(m0 + p * 32 + rloc) * 256 + col0) = v;
        }
    }
}

// ---------------- gemm1: y1 = X @ W1b^T + b1, stats fused ---------------------
// 512 thr = 8 waves (2m x 4n of 64x64), full N=256. A via global_load_lds dbuf
// (16 KB only -> 2 blocks/CU co-resident); B=W1b fragments straight from L2.
__global__ __launch_bounds__(512, 4) void gemm_bn1(
    const unsigned short* __restrict__ X,
    const unsigned short* __restrict__ W1b,
    const float* __restrict__ b1,
    unsigned short* __restrict__ Y1,
    float* __restrict__ Psum, float* __restrict__ Psq)
{
    __shared__ short smem[8192];   // 16 KB: A dbuf (2 x 4096 shorts) / epilogue
    const int tid  = threadIdx.x;
    const int wave = tid >> 6, lane = tid & 63;
    const int wm   = wave & 1, wn = wave >> 1;
    const int quad = lane >> 4, l16 = lane & 15;
    const long m0 = (long)blockIdx.x * 128;

    const int srow = tid >> 2;
    const int cgs  = ((tid & 3) ^ ((tid >> 3) & 3)) * 8;
    const size_t aoff = (size_t)(m0 + srow) * KD1 + cgs;

    floatx4 acc[4][4];
#pragma unroll
    for (int a = 0; a < 4; a++)
#pragma unroll
        for (int b = 0; b < 4; b++)
            acc[a][b] = floatx4{0.f, 0.f, 0.f, 0.f};

    const int rsw = (l16 >> 1) & 3;
    const unsigned short* Bp1 = W1b + (size_t)(wn * 64 + l16) * KD1 + quad * 8;

#define STAGE_A(buf, ck)                                                        \
    __builtin_amdgcn_global_load_lds((gas_t)(const void*)(X + aoff + (ck)*32),  \
        (las_t)(void*)(smem + (buf)*4096 + wave*512), 16, 0, 0)

    STAGE_A(0, 0);
    __syncthreads();
    for (int ck = 0; ck < 12; ck++) {
        const int cur = ck & 1;
        if (ck + 1 < 12) STAGE_A(cur ^ 1, ck + 1);
        short8 af[4], bfr[4];
#pragma unroll
        for (int nb = 0; nb < 4; nb++)
            bfr[nb] = *(const short8*)(Bp1 + (size_t)nb * 16 * KD1 + ck * 32);
#pragma unroll
        for (int mb = 0; mb < 4; mb++)
            af[mb] = *(const short8*)(smem + cur * 4096 +
                        (wm * 64 + mb * 16 + l16) * 32 + ((quad ^ rsw) * 8));
#pragma unroll
        for (int mb = 0; mb < 4; mb++)
#pragma unroll
            for (int nb = 0; nb < 4; nb++)
                acc[mb][nb] = __builtin_amdgcn_mfma_f32_16x16x32_bf16(af[mb], bfr[nb], acc[mb][nb], 0, 0, 0);
        __syncthreads();
    }
#undef STAGE_A

    gemm_epilogue(smem, acc, b1, Y1, Psum, Psq, m0, tid, wm, wn, quad, l16,
                  blockIdx.x * 2 + wm);
}

// ---------------- gemm2: y2 = relu(BN1(y1)) @ W2b^T + b2, BN1 fused on load --
// A-staging: coalesced b128 reg-load of y1 -> BN1+relu+pack bf16 in-register ->
// ds_write_b128 (16 KB dbuf). Numerically identical to the old bn_apply kernel.
__global__ __launch_bounds__(512, 4) void gemm_bn2(
    const unsigned short* __restrict__ Y1in,
    const unsigned short* __restrict__ W2b,
    const float* __restrict__ SC1, const float* __restrict__ SH1,
    const float* __restrict__ b2,
    unsigned short* __restrict__ Y2out,
    float* __restrict__ Psum, float* __restrict__ Psq)
{
    __shared__ short smem[8192];   // 16 KB: x2 dbuf (2 x 4096 shorts) / epilogue
    const int tid  = threadIdx.x;
    const int wave = tid >> 6, lane = tid & 63;
    const int wm   = wave & 1, wn = wave >> 1;
    const int quad = lane >> 4, l16 = lane & 15;
    const long m0 = (long)blockIdx.x * 128;

    const int srow = tid >> 2;
    const int cgs  = ((tid & 3) ^ ((tid >> 3) & 3)) * 8;   // col-chunk base (8 cols)
    const unsigned short* Ap = Y1in + (size_t)(m0 + srow) * 256 + cgs;

    floatx4 acc[4][4];
#pragma unroll
    for (int a = 0; a < 4; a++)
#pragma unroll
        for (int b = 0; b < 4; b++)
            acc[a][b] = floatx4{0.f, 0.f, 0.f, 0.f};

    const int rsw = (l16 >> 1) & 3;
    const unsigned short* Bp2 = W2b + (size_t)(wn * 64 + l16) * 256 + quad * 8;

    // load + BN1-transform + LDS-write of one 32-col chunk
#define XFORM(buf, ck) do {                                                     \
        ushort4 r0 = *(const ushort4*)(Ap + (ck) * 32);                         \
        ushort4 r1 = *(const ushort4*)(Ap + (ck) * 32 + 4);                     \
        const int c0 = (ck) * 32 + cgs;                                         \
        float4 s0 = *(const float4*)(SC1 + c0), s1 = *(const float4*)(SC1 + c0 + 4); \
        float4 h0 = *(const float4*)(SH1 + c0), h1 = *(const float4*)(SH1 + c0 + 4); \
        short8 o;                                                               \
        o[0] = (short)f2b(fmaxf(fmaf(b2f(r0.x), s0.x, h0.x), 0.f));             \
        o[1] = (short)f2b(fmaxf(fmaf(b2f(r0.y), s0.y, h0.y), 0.f));             \
        o[2] = (short)f2b(fmaxf(fmaf(b2f(r0.z), s0.z, h0.z), 0.f));             \
        o[3] = (short)f2b(fmaxf(fmaf(b2f(r0.w), s0.w, h0.w), 0.f));             \
        o[4] = (short)f2b(fmaxf(fmaf(b2f(r1.x), s1.x, h1.x), 0.f));             \
        o[5] = (short)f2b(fmaxf(fmaf(b2f(r1.y), s1.y, h1.y), 0.f));             \
        o[6] = (short)f2b(fmaxf(fmaf(b2f(r1.z), s1.z, h1.z), 0.f));             \
        o[7] = (short)f2b(fmaxf(fmaf(b2f(r1.w), s1.w, h1.w), 0.f));             \
        *(short8*)(smem + (buf) * 4096 + wave * 512 + lane * 8) = o;            \
    } while (0)

    XFORM(0, 0);
    __syncthreads();
    for (int ck = 0; ck < 8; ck++) {
        const int cur = ck & 1;
        short8 af[4], bfr[4];
#pragma unroll
        for (int nb = 0; nb < 4; nb++)
            bfr[nb] = *(const short8*)(Bp2 + (size_t)nb * 16 * 256 + ck * 32);
#pragma unroll
        for (int mb = 0; mb < 4; mb++)
            af[mb] = *(const short8*)(smem + cur * 4096 +
                        (wm * 64 + mb * 16 + l16) * 32 + ((quad ^ rsw) * 8));
#pragma unroll
        for (int mb = 0; mb < 4; mb++)
#pragma unroll
            for (int nb = 0; nb < 4; nb++)
                acc[mb][nb] = __builtin_amdgcn_mfma_f32_16x16x32_bf16(af[mb], bfr[nb], acc[mb][nb], 0, 0, 0);
        if (ck + 1 < 8) XFORM(cur ^ 1, ck + 1);
        __syncthreads();
    }
#undef XFORM

    gemm_epilogue(smem, acc, b2, Y2out, Psum, Psq, m0, tid, wm, wn, quad, l16,
                  blockIdx.x * 2 + wm);
}

// ---------------- BN finalize: reduce P[1024][256] -> scale/shift --------
__global__ __launch_bounds__(256) void finalize_bn(
    const float* __restrict__ Psum, const float* __restrict__ Psq,
    const float* __restrict__ g, const float* __restrict__ beta,
    float* __restrict__ scale, float* __restrict__ shift)
{
    __shared__ float ls[8][32], lq[8][32];
    const int cl = threadIdx.x & 31, grp = threadIdx.x >> 5;
    const int c = blockIdx.x * 32 + cl;
    float s = 0.f, q = 0.f;
    for (int k = grp * 128; k < grp * 128 + 128; k++) {
        s += Psum[k * 256 + c];
        q += Psq [k * 256 + c];
    }
    ls[grp][cl] = s; lq[grp][cl] = q;
    __syncthreads();
    if (grp == 0) {
#pragma unroll
        for (int k = 1; k < 8; k++) { s += ls[k][cl]; q += lq[k][cl]; }
        float m  = s * (1.0f / (float)NQ);
        float v  = q * (1.0f / (float)NQ) - m * m;
        float rs = rsqrtf(v + 1e-5f);
        float a  = rs * g[c];
        scale[c] = a;
        shift[c] = fmaf(-m, a, beta[c]);
    }
}

// ---------------- final BN apply + relu: y2 bf16 -> d_out fp32 ----------------
__global__ __launch_bounds__(256) void final_apply(
    const unsigned short* __restrict__ y2, const float* __restrict__ scale,
    const float* __restrict__ shift, float* __restrict__ out)
{
    size_t t = (size_t)blockIdx.x * 256 + threadIdx.x;   // 2,097,152 threads x 8 elems
    int c = ((int)t & 31) * 8;
    const ushort4* in = (const ushort4*)y2 + t * 2;
    ushort4 a = in[0], b = in[1];
    float4 s0 = *(const float4*)(scale + c), s1 = *(const float4*)(scale + c + 4);
    float4 h0 = *(const float4*)(shift + c), h1 = *(const float4*)(shift + c + 4);
    float4 o0, o1;
    o0.x = fmaxf(fmaf(b2f(a.x), s0.x, h0.x), 0.f);
    o0.y = fmaxf(fmaf(b2f(a.y), s0.y, h0.y), 0.f);
    o0.z = fmaxf(fmaf(b2f(a.z), s0.z, h0.z), 0.f);
    o0.w = fmaxf(fmaf(b2f(a.w), s0.w, h0.w), 0.f);
    o1.x = fmaxf(fmaf(b2f(b.x), s1.x, h1.x), 0.f);
    o1.y = fmaxf(fmaf(b2f(b.y), s1.y, h1.y), 0.f);
    o1.z = fmaxf(fmaf(b2f(b.z), s1.z, h1.z), 0.f);
    o1.w = fmaxf(fmaf(b2f(b.w), s1.w, h1.w), 0.f);
    ((float4*)out)[t * 2]     = o0;
    ((float4*)out)[t * 2 + 1] = o1;
}

extern "C" void kernel_launch(void* const* d_in, const int* in_sizes, int n_in,
                              void* d_out, int out_size, void* d_ws, size_t ws_size,
                              hipStream_t stream) {
    (void)in_sizes; (void)n_in; (void)out_size; (void)ws_size;
    const float* xyz1 = (const float*)d_in[0];
    const float* xyz2 = (const float*)d_in[1];
    const float* f1   = (const float*)d_in[2];
    const float* f2   = (const float*)d_in[3];
    const float* W1   = (const float*)d_in[4];
    const float* b1   = (const float*)d_in[5];
    const float* g1   = (const float*)d_in[6];
    const float* be1  = (const float*)d_in[7];
    const float* W2   = (const float*)d_in[8];
    const float* b2   = (const float*)d_in[9];
    const float* g2   = (const float*)d_in[10];
    const float* be2  = (const float*)d_in[11];

    char* ws = (char*)d_ws;
    unsigned short* X    = (unsigned short*)(ws + X_OFF);
    unsigned short* Y1   = (unsigned short*)(ws + Y1_OFF);    // y1, reused as y2
    float*          SC1  = (float*)(ws + SCALE1_OFF);
    float*          SH1  = (float*)(ws + SHIFT1_OFF);
    float*          SC2  = (float*)(ws + SCALE2_OFF);
    float*          SH2  = (float*)(ws + SHIFT2_OFF);
    unsigned short* W1b  = (unsigned short*)(ws + W1B_OFF);
    unsigned short* W2b  = (unsigned short*)(ws + W2B_OFF);
    float*          PS   = (float*)(ws + PS_OFF);
    float*          PQ   = (float*)(ws + PQ_OFF);

    knn_interp_kernel<<<1664, 256, 0, stream>>>(xyz1, xyz2, f1, f2, W1, W2, W1b, W2b, X);
    gemm_bn1<<<512, 512, 0, stream>>>(X, W1b, b1, Y1, PS, PQ);
    finalize_bn<<<8, 256, 0, stream>>>(PS, PQ, g1, be1, SC1, SH1);
    gemm_bn2<<<512, 512, 0, stream>>>(Y1, W2b, SC1, SH1, b2, Y1, PS, PQ);
    finalize_bn<<<8, 256, 0, stream>>>(PS, PQ, g2, be2, SC2, SH2);
    final_apply<<<(NQ * DH) / (8 * 256), 256, 0, stream>>>(Y1, SC2, SH2, (float*)d_out);
}

// Round 11
// 245.865 us; speedup vs baseline: 1.1396x; 1.1396x over previous
//
#include <hip/hip_runtime.h>
#include <hip/hip_bf16.h>

// Problem constants (fixed by setup_inputs)
#define B_    16
#define N1    1024
#define NP    4096
#define D1c   256
#define D2c   128
#define DH    256
#define NQ    (B_*NP)        // 65536 rows
#define KD1   (D1c+D2c)      // 384

// Workspace layout (bytes).
#define X_OFF      0ul                     // x bf16: 65536*384*2
#define Y1_OFF     50331648ul              // y1 / y2 bf16: 65536*256*2
#define SCALE1_OFF 85458944ul
#define SHIFT1_OFF (SCALE1_OFF+1024ul)
#define SCALE2_OFF (SCALE1_OFF+2048ul)
#define SHIFT2_OFF (SCALE1_OFF+3072ul)
#define W1B_OFF    85467136ul              // bf16 W1: 256*384*2
#define W2B_OFF    85663744ul              // bf16 W2: 256*256*2
#define PS_OFF     85794816ul              // float Psum[1024][256] = 1 MB
#define PQ_OFF     86843392ul              // float Psq [1024][256] = 1 MB

using short8  = __attribute__((ext_vector_type(8))) short;
using floatx4 = __attribute__((ext_vector_type(4))) float;
using f4v     = __attribute__((ext_vector_type(4))) float;
using f2v     = __attribute__((ext_vector_type(2))) float;
typedef const __attribute__((address_space(1))) unsigned int* gas_t;
typedef __attribute__((address_space(3))) unsigned int* las_t;
typedef const __attribute__((address_space(4))) float* c4f_t;   // constant AS -> s_load
typedef const __attribute__((address_space(4))) f4v*   c4v_t;

// bf16 RNE cast (bit-level, matches np/jax round-to-nearest-even; inputs finite)
static __device__ __forceinline__ unsigned short f2b(float f) {
    unsigned int u = __builtin_bit_cast(unsigned int, f);
    return (unsigned short)((u + 0x7FFFu + ((u >> 16) & 1u)) >> 16);
}
static __device__ __forceinline__ float b2f(unsigned short u) {
    unsigned int x = ((unsigned int)u) << 16;
    return __builtin_bit_cast(float, x);
}

// ---------------- fused kNN + interp/concat (+ weight cvt on spare blocks) ----
// (unchanged from R6: XCD-affinity remap, scalar candidate loads, packed
// distances, min/med3 selection, exact top_k tie semantics)
__global__ __launch_bounds__(256) void knn_interp_kernel(
    const float* __restrict__ xyz1, const float* __restrict__ xyz2,
    const float* __restrict__ f1,   const float* __restrict__ feat2,
    const float* __restrict__ W1,   const float* __restrict__ W2,
    unsigned short* __restrict__ W1b, unsigned short* __restrict__ W2b,
    unsigned short* __restrict__ x)
{
#pragma clang fp contract(off)
    const int tid = threadIdx.x;
    if (blockIdx.x >= 1024) {            // ---- weight conversion blocks ----
        int i = (blockIdx.x - 1024) * 256 + tid;
        if (i < DH * KD1) W1b[i] = f2b(W1[i]);
        else              W2b[i - DH * KD1] = f2b(W2[i - DH * KD1]);
        return;
    }

    __shared__ float pd[12 * 64];
    __shared__ int   pi[12 * 64];
    __shared__ int   sidx[64 * 3];
    __shared__ float swt [64 * 3];

    const int xcd  = blockIdx.x & 7;
    const int slot = blockIdx.x >> 3;          // 0..127
    const int batch = xcd * 2 + (slot >> 6);
    const int qblk  = slot & 63;

    const int ql  = tid & 63;
    const int seg = tid >> 6;
    const int seg_u = __builtin_amdgcn_readfirstlane(seg);
    const int n = batch * NP + qblk * 64 + ql;
    const float* qp = xyz2 + (size_t)n * 3;
    const float qx = qp[0], qy = qp[1], qz = qp[2];
    const f2v qx2 = {qx, qx}, qy2 = {qy, qy}, qz2 = {qz, qz};

    c4f_t cp = (c4f_t)(const void*)(xyz1 + (size_t)batch * (N1 * 3))
               + (size_t)seg_u * 768;

    float d0 = 3.4e38f, d1v = 3.4e38f, d2v = 3.4e38f;
    int   i0 = 0, i1 = 0, i2 = 0;

#define SEL(jj, dd) do {                                                      \
        bool c0 = (dd) < d0, c1 = (dd) < d1v, c2 = (dd) < d2v;                \
        i2 = c2 ? (c1 ? i1 : (jj)) : i2;                                      \
        i1 = c1 ? (c0 ? i0 : (jj)) : i1;                                      \
        i0 = c0 ? (jj) : i0;                                                  \
        d2v = __builtin_amdgcn_fmed3f(d1v, d2v, (dd));                        \
        d1v = __builtin_amdgcn_fmed3f(d0, d1v, (dd));                         \
        d0  = fminf(d0, (dd));                                                \
    } while (0)

    const int jbase = seg_u * 256;
    for (int j = 0; j < 256; j += 4) {
        f4v p0 = *(c4v_t)(cp + j * 3);
        f4v p1 = *(c4v_t)(cp + j * 3 + 4);
        f4v p2 = *(c4v_t)(cp + j * 3 + 8);
        {
            f2v cx2 = {p0.x, p0.w}, cy2 = {p0.y, p1.x}, cz2 = {p0.z, p1.y};
            f2v dx2 = qx2 - cx2, dy2 = qy2 - cy2, dz2 = qz2 - cz2;
            f2v dd2 = (dx2 * dx2 + dy2 * dy2) + dz2 * dz2;
            SEL(jbase + j + 0, dd2.x);
            SEL(jbase + j + 1, dd2.y);
        }
        {
            f2v cx2 = {p1.z, p2.y}, cy2 = {p1.w, p2.z}, cz2 = {p2.x, p2.w};
            f2v dx2 = qx2 - cx2, dy2 = qy2 - cy2, dz2 = qz2 - cz2;
            f2v dd2 = (dx2 * dx2 + dy2 * dy2) + dz2 * dz2;
            SEL(jbase + j + 2, dd2.x);
            SEL(jbase + j + 3, dd2.y);
        }
    }
#undef SEL

    pd[(seg * 3 + 0) * 64 + ql] = d0;   pi[(seg * 3 + 0) * 64 + ql] = i0;
    pd[(seg * 3 + 1) * 64 + ql] = d1v;  pi[(seg * 3 + 1) * 64 + ql] = i1;
    pd[(seg * 3 + 2) * 64 + ql] = d2v;  pi[(seg * 3 + 2) * 64 + ql] = i2;
    __syncthreads();

    if (tid < 64) {
        float e0 = pd[0 * 64 + tid], e1 = pd[1 * 64 + tid], e2 = pd[2 * 64 + tid];
        int   j0 = pi[0 * 64 + tid], j1 = pi[1 * 64 + tid], j2 = pi[2 * 64 + tid];
#pragma unroll
        for (int s = 3; s < 12; s++) {
            float d = pd[s * 64 + tid];
            int   i = pi[s * 64 + tid];
            bool c2 = d < e2;
            e2 = c2 ? d : e2;  j2 = c2 ? i : j2;
            bool c1 = e2 < e1;
            float tf = e1; e1 = c1 ? e2 : e1; e2 = c1 ? tf : e2;
            int   ti = j1; j1 = c1 ? j2 : j1; j2 = c1 ? ti : j2;
            bool c0 = e1 < e0;
            tf = e0; e0 = c0 ? e1 : e0; e1 = c0 ? tf : e1;
            ti = j0; j0 = c0 ? j1 : j0; j1 = c0 ? ti : j1;
        }
        const float eps = 1.1920929e-07f;
        float v0 = 1.0f / __fadd_rn(e0, eps);
        float v1 = 1.0f / __fadd_rn(e1, eps);
        float v2 = 1.0f / __fadd_rn(e2, eps);
        float s  = __fadd_rn(__fadd_rn(v0, v1), v2);
        sidx[tid * 3 + 0] = j0;  swt[tid * 3 + 0] = v0 / s;
        sidx[tid * 3 + 1] = j1;  swt[tid * 3 + 1] = v1 / s;
        sidx[tid * 3 + 2] = j2;  swt[tid * 3 + 2] = v2 / s;
    }
    __syncthreads();

    const int lane = tid & 63, wv = tid >> 6;
    const float* fb = f1 + (size_t)batch * (N1 * D1c);
#pragma unroll 4
    for (int it = 0; it < 16; it++) {
        const int q  = wv * 16 + it;
        const int nr = batch * NP + qblk * 64 + q;
        const int a0 = sidx[q * 3 + 0], a1 = sidx[q * 3 + 1], a2 = sidx[q * 3 + 2];
        const float w0 = swt[q * 3 + 0], w1 = swt[q * 3 + 1], w2 = swt[q * 3 + 2];
        float4 a = *(const float4*)(fb + (size_t)a0 * D1c + lane * 4);
        float4 b = *(const float4*)(fb + (size_t)a1 * D1c + lane * 4);
        float4 c = *(const float4*)(fb + (size_t)a2 * D1c + lane * 4);
        ushort4 o;
        o.x = f2b(__fadd_rn(__fadd_rn(__fmul_rn(a.x,w0), __fmul_rn(b.x,w1)), __fmul_rn(c.x,w2)));
        o.y = f2b(__fadd_rn(__fadd_rn(__fmul_rn(a.y,w0), __fmul_rn(b.y,w1)), __fmul_rn(c.y,w2)));
        o.z = f2b(__fadd_rn(__fadd_rn(__fmul_rn(a.z,w0), __fmul_rn(b.z,w1)), __fmul_rn(c.z,w2)));
        o.w = f2b(__fadd_rn(__fadd_rn(__fmul_rn(a.w,w0), __fmul_rn(b.w,w1)), __fmul_rn(c.w,w2)));
        *(ushort4*)(x + (size_t)nr * KD1 + lane * 4) = o;
        float2 f = *(const float2*)(feat2 + (size_t)nr * D2c + lane * 2);
        ushort2 o2; o2.x = f2b(f.x); o2.y = f2b(f.y);
        *(ushort2*)(x + (size_t)nr * KD1 + D1c + lane * 2) = o2;
    }
}

// ---------------- shared gemm epilogue (R6-proven): stats + LDS-transpose -----
// smem: >= 16384 shorts. 2 passes of 64 rows, contiguous 16 B stores.
static __device__ __forceinline__ void gemm_epilogue(
    short* smem, floatx4 (&acc)[4][4], const float* __restrict__ bias,
    unsigned short* __restrict__ Out, float* __restrict__ Psum, float* __restrict__ Psq,
    long m0, int tid, int wm, int wn, int quad, int l16, int pslot)
{
#pragma unroll
    for (int nb = 0; nb < 4; nb++) {
        const int col = wn * 64 + nb * 16 + l16;
        const float bia = bias[col];
        float s = 0.f, q = 0.f;
#pragma unroll
        for (int mb = 0; mb < 4; mb++)
#pragma unroll
            for (int r = 0; r < 4; r++) {
                float v = acc[mb][nb][r] + bia;
                acc[mb][nb][r] = v;
                s += v; q += v * v;
            }
        s += __shfl_xor(s, 16); s += __shfl_xor(s, 32);
        q += __shfl_xor(q, 16); q += __shfl_xor(q, 32);
        if (quad == 0) {
            Psum[pslot * 256 + col] = s;
            Psq [pslot * 256 + col] = q;
        }
    }

#pragma unroll
    for (int p = 0; p < 2; p++) {
        __syncthreads();
        if (wm == p) {
#pragma unroll
            for (int mb = 0; mb < 4; mb++)
#pragma unroll
                for (int r = 0; r < 4; r++) {
                    const int rl = mb * 16 + quad * 4 + r;
#pragma unroll
                    for (int nb = 0; nb < 4; nb++) {
                        const int col = wn * 64 + nb * 16 + l16;
                        smem[rl * 256 + ((((col >> 3) + rl) & 31) << 3) + (col & 7)] =
                            (short)f2b(acc[mb][nb][r]);
                    }
                }
        }
        __syncthreads();
#pragma unroll
        for (int rr = 0; rr < 4; rr++) {
            const int rl = rr * 16 + (tid >> 5);
            const int c  = tid & 31;
            short8 v = *(const short8*)(smem + rl * 256 + (((c + rl) & 31) << 3));
            *(short8*)(Out + (size_t)(m0 + p * 64 + rl) * 256 + c * 8) = v;
        }
    }
}

// ---------------- gemm1: y1 = X @ W1b^T + b1, stats fused (R6 structure) ------
// 512 thr = 8 waves (2m x 4n of 64x64), full N=256 per block. 48 KB LDS:
// A dbuf (2x8 KB) + B dbuf (2x16 KB), single-barrier stage-ahead.
__global__ __launch_bounds__(512, 2) void gemm_bn1(
    const unsigned short* __restrict__ A,
    const unsigned short* __restrict__ Bw,
    const float* __restrict__ bias,
    unsigned short* __restrict__ Out,
    float* __restrict__ Psum, float* __restrict__ Psq)
{
    __shared__ short smem[24576];   // 48 KB: As[2] @ 0/4096, Bs[2] @ 8192/16384
    const int tid  = threadIdx.x;
    const int wave = tid >> 6, lane = tid & 63;
    const int wm   = wave & 1, wn = wave >> 1;
    const int quad = lane >> 4, l16 = lane & 15;
    const long m0 = (long)blockIdx.x * 128;

    const int srow = tid >> 2;
    const int cg   = ((tid & 3) ^ ((tid >> 3) & 3)) * 8;
    const size_t aoff  = (size_t)(m0 + srow) * KD1 + cg;
    const size_t boff0 = (size_t)(srow) * KD1 + cg;
    const size_t boff1 = (size_t)(128 + srow) * KD1 + cg;

    floatx4 acc[4][4];
#pragma unroll
    for (int a = 0; a < 4; a++)
#pragma unroll
        for (int b = 0; b < 4; b++)
            acc[a][b] = floatx4{0.f, 0.f, 0.f, 0.f};

    const int rsw = (l16 >> 1) & 3;

#define STAGE(buf, ck) do {                                                         \
        __builtin_amdgcn_global_load_lds((gas_t)(const void*)(A + aoff + (ck)*32),  \
            (las_t)(void*)(smem + (buf)*4096 + wave*512), 16, 0, 0);                \
        __builtin_amdgcn_global_load_lds((gas_t)(const void*)(Bw + boff0 + (ck)*32),\
            (las_t)(void*)(smem + 8192 + (buf)*8192 + wave*512), 16, 0, 0);         \
        __builtin_amdgcn_global_load_lds((gas_t)(const void*)(Bw + boff1 + (ck)*32),\
            (las_t)(void*)(smem + 8192 + (buf)*8192 + 4096 + wave*512), 16, 0, 0);  \
    } while (0)

    STAGE(0, 0);
    __syncthreads();
    for (int ck = 0; ck < 12; ck++) {
        const int cur = ck & 1;
        if (ck + 1 < 12) STAGE(cur ^ 1, ck + 1);
        const short* Ab = smem + cur * 4096;
        const short* Bb = smem + 8192 + cur * 8192;
        short8 af[4], bfr[4];
#pragma unroll
        for (int mb = 0; mb < 4; mb++)
            af[mb] = *(const short8*)(Ab + (wm * 64 + mb * 16 + l16) * 32 + ((quad ^ rsw) * 8));
#pragma unroll
        for (int nb = 0; nb < 4; nb++)
            bfr[nb] = *(const short8*)(Bb + (wn * 64 + nb * 16 + l16) * 32 + ((quad ^ rsw) * 8));
#pragma unroll
        for (int mb = 0; mb < 4; mb++)
#pragma unroll
            for (int nb = 0; nb < 4; nb++)
                acc[mb][nb] = __builtin_amdgcn_mfma_f32_16x16x32_bf16(af[mb], bfr[nb], acc[mb][nb], 0, 0, 0);
        __syncthreads();
    }
#undef STAGE

    gemm_epilogue(smem, acc, bias, Out, Psum, Psq, m0, tid, wm, wn, quad, l16,
                  blockIdx.x * 2 + wm);
}

// ---------------- gemm2: y2 = relu(BN1(y1)) @ W2b^T + b2, BN1 fused on load ---
// Same R6 structure; only A-staging differs: early b128 reg-load of y1 (latency
// hidden behind current chunk's MFMAs) -> BN1+relu+pack -> ds_write_b128 into
// the identical LDS slot. B staged async via global_load_lds (unchanged).
__global__ __launch_bounds__(512, 2) void gemm_bn2(
    const unsigned short* __restrict__ Y1in,
    const unsigned short* __restrict__ W2b,
    const float* __restrict__ SC1, const float* __restrict__ SH1,
    const float* __restrict__ b2,
    unsigned short* __restrict__ Y2out,
    float* __restrict__ Psum, float* __restrict__ Psq)
{
    __shared__ short smem[24576];   // 48 KB: As[2] @ 0/4096, Bs[2] @ 8192/16384
    const int tid  = threadIdx.x;
    const int wave = tid >> 6, lane = tid & 63;
    const int wm   = wave & 1, wn = wave >> 1;
    const int quad = lane >> 4, l16 = lane & 15;
    const long m0 = (long)blockIdx.x * 128;

    const int srow = tid >> 2;
    const int cg   = ((tid & 3) ^ ((tid >> 3) & 3)) * 8;   // source col-chunk base
    const unsigned short* Ap = Y1in + (size_t)(m0 + srow) * 256 + cg;
    const size_t boff0 = (size_t)(srow) * 256 + cg;
    const size_t boff1 = (size_t)(128 + srow) * 256 + cg;

    floatx4 acc[4][4];
#pragma unroll
    for (int a = 0; a < 4; a++)
#pragma unroll
        for (int b = 0; b < 4; b++)
            acc[a][b] = floatx4{0.f, 0.f, 0.f, 0.f};

    const int rsw = (l16 >> 1) & 3;

#define STAGE_B(buf, ck) do {                                                        \
        __builtin_amdgcn_global_load_lds((gas_t)(const void*)(W2b + boff0 + (ck)*32),\
            (las_t)(void*)(smem + 8192 + (buf)*8192 + wave*512), 16, 0, 0);          \
        __builtin_amdgcn_global_load_lds((gas_t)(const void*)(W2b + boff1 + (ck)*32),\
            (las_t)(void*)(smem + 8192 + (buf)*8192 + 4096 + wave*512), 16, 0, 0);   \
    } while (0)

    // transform-write of A chunk ck into buffer buf (regs r0,r1 pre-loaded)
#define XSTORE(buf, ck, r0, r1) do {                                            \
        const int c0 = (ck) * 32 + cg;                                          \
        float4 s0 = *(const float4*)(SC1 + c0), s1 = *(const float4*)(SC1 + c0 + 4); \
        float4 h0 = *(const float4*)(SH1 + c0), h1 = *(const float4*)(SH1 + c0 + 4); \
        short8 o;                                                               \
        o[0] = (short)f2b(fmaxf(fmaf(b2f(r0.x), s0.x, h0.x), 0.f));             \
        o[1] = (short)f2b(fmaxf(fmaf(b2f(r0.y), s0.y, h0.y), 0.f));             \
        o[2] = (short)f2b(fmaxf(fmaf(b2f(r0.z), s0.z, h0.z), 0.f));             \
        o[3] = (short)f2b(fmaxf(fmaf(b2f(r0.w), s0.w, h0.w), 0.f));             \
        o[4] = (short)f2b(fmaxf(fmaf(b2f(r1.x), s1.x, h1.x), 0.f));             \
        o[5] = (short)f2b(fmaxf(fmaf(b2f(r1.y), s1.y, h1.y), 0.f));             \
        o[6] = (short)f2b(fmaxf(fmaf(b2f(r1.z), s1.z, h1.z), 0.f));             \
        o[7] = (short)f2b(fmaxf(fmaf(b2f(r1.w), s1.w, h1.w), 0.f));             \
        *(short8*)(smem + (buf) * 4096 + wave * 512 + lane * 8) = o;            \
    } while (0)

    {
        ushort4 r0 = *(const ushort4*)(Ap);
        ushort4 r1 = *(const ushort4*)(Ap + 4);
        XSTORE(0, 0, r0, r1);
        STAGE_B(0, 0);
    }
    __syncthreads();
    for (int ck = 0; ck < 8; ck++) {
        const int cur = ck & 1;
        ushort4 r0, r1;
        if (ck + 1 < 8) {                       // issue next-A loads + B stage early
            r0 = *(const ushort4*)(Ap + (ck + 1) * 32);
            r1 = *(const ushort4*)(Ap + (ck + 1) * 32 + 4);
            STAGE_B(cur ^ 1, ck + 1);
        }
        const short* Ab = smem + cur * 4096;
        const short* Bb = smem + 8192 + cur * 8192;
        short8 af[4], bfr[4];
#pragma unroll
        for (int mb = 0; mb < 4; mb++)
            af[mb] = *(const short8*)(Ab + (wm * 64 + mb * 16 + l16) * 32 + ((quad ^ rsw) * 8));
#pragma unroll
        for (int nb = 0; nb < 4; nb++)
            bfr[nb] = *(const short8*)(Bb + (wn * 64 + nb * 16 + l16) * 32 + ((quad ^ rsw) * 8));
#pragma unroll
        for (int mb = 0; mb < 4; mb++)
#pragma unroll
            for (int nb = 0; nb < 4; nb++)
                acc[mb][nb] = __builtin_amdgcn_mfma_f32_16x16x32_bf16(af[mb], bfr[nb], acc[mb][nb], 0, 0, 0);
        if (ck + 1 < 8) XSTORE(cur ^ 1, ck + 1, r0, r1);   // transform after MFMAs
        __syncthreads();
    }
#undef XSTORE
#undef STAGE_B

    gemm_epilogue(smem, acc, b2, Y2out, Psum, Psq, m0, tid, wm, wn, quad, l16,
                  blockIdx.x * 2 + wm);
}

// ---------------- BN finalize: reduce P[1024][256] -> scale/shift --------
__global__ __launch_bounds__(256) void finalize_bn(
    const float* __restrict__ Psum, const float* __restrict__ Psq,
    const float* __restrict__ g, const float* __restrict__ beta,
    float* __restrict__ scale, float* __restrict__ shift)
{
    __shared__ float ls[8][32], lq[8][32];
    const int cl = threadIdx.x & 31, grp = threadIdx.x >> 5;
    const int c = blockIdx.x * 32 + cl;
    float s = 0.f, q = 0.f;
    for (int k = grp * 128; k < grp * 128 + 128; k++) {
        s += Psum[k * 256 + c];
        q += Psq [k * 256 + c];
    }
    ls[grp][cl] = s; lq[grp][cl] = q;
    __syncthreads();
    if (grp == 0) {
#pragma unroll
        for (int k = 1; k < 8; k++) { s += ls[k][cl]; q += lq[k][cl]; }
        float m  = s * (1.0f / (float)NQ);
        float v  = q * (1.0f / (float)NQ) - m * m;
        float rs = rsqrtf(v + 1e-5f);
        float a  = rs * g[c];
        scale[c] = a;
        shift[c] = fmaf(-m, a, beta[c]);
    }
}

// ---------------- final BN apply + relu: y2 bf16 -> d_out fp32 ----------------
__global__ __launch_bounds__(256) void final_apply(
    const unsigned short* __restrict__ y2, const float* __restrict__ scale,
    const float* __restrict__ shift, float* __restrict__ out)
{
    size_t t = (size_t)blockIdx.x * 256 + threadIdx.x;   // 2,097,152 threads x 8 elems
    int c = ((int)t & 31) * 8;
    const ushort4* in = (const ushort4*)y2 + t * 2;
    ushort4 a = in[0], b = in[1];
    float4 s0 = *(const float4*)(scale + c), s1 = *(const float4*)(scale + c + 4);
    float4 h0 = *(const float4*)(shift + c), h1 = *(const float4*)(shift + c + 4);
    float4 o0, o1;
    o0.x = fmaxf(fmaf(b2f(a.x), s0.x, h0.x), 0.f);
    o0.y = fmaxf(fmaf(b2f(a.y), s0.y, h0.y), 0.f);
    o0.z = fmaxf(fmaf(b2f(a.z), s0.z, h0.z), 0.f);
    o0.w = fmaxf(fmaf(b2f(a.w), s0.w, h0.w), 0.f);
    o1.x = fmaxf(fmaf(b2f(b.x), s1.x, h1.x), 0.f);
    o1.y = fmaxf(fmaf(b2f(b.y), s1.y, h1.y), 0.f);
    o1.z = fmaxf(fmaf(b2f(b.z), s1.z, h1.z), 0.f);
    o1.w = fmaxf(fmaf(b2f(b.w), s1.w, h1.w), 0.f);
    ((float4*)out)[t * 2]     = o0;
    ((float4*)out)[t * 2 + 1] = o1;
}

extern "C" void kernel_launch(void* const* d_in, const int* in_sizes, int n_in,
                              void* d_out, int out_size, void* d_ws, size_t ws_size,
                              hipStream_t stream) {
    (void)in_sizes; (void)n_in; (void)out_size; (void)ws_size;
    const float* xyz1 = (const float*)d_in[0];
    const float* xyz2 = (const float*)d_in[1];
    const float* f1   = (const float*)d_in[2];
    const float* f2   = (const float*)d_in[3];
    const float* W1   = (const float*)d_in[4];
    const float* b1   = (const float*)d_in[5];
    const float* g1   = (const float*)d_in[6];
    const float* be1  = (const float*)d_in[7];
    const float* W2   = (const float*)d_in[8];
    const float* b2   = (const float*)d_in[9];
    const float* g2   = (const float*)d_in[10];
    const float* be2  = (const float*)d_in[11];

    char* ws = (char*)d_ws;
    unsigned short* X    = (unsigned short*)(ws + X_OFF);
    unsigned short* Y1   = (unsigned short*)(ws + Y1_OFF);    // y1, reused as y2
    float*          SC1  = (float*)(ws + SCALE1_OFF);
    float*          SH1  = (float*)(ws + SHIFT1_OFF);
    float*          SC2  = (float*)(ws + SCALE2_OFF);
    float*          SH2  = (float*)(ws + SHIFT2_OFF);
    unsigned short* W1b  = (unsigned short*)(ws + W1B_OFF);
    unsigned short* W2b  = (unsigned short*)(ws + W2B_OFF);
    float*          PS   = (float*)(ws + PS_OFF);
    float*          PQ   = (float*)(ws + PQ_OFF);

    knn_interp_kernel<<<1664, 256, 0, stream>>>(xyz1, xyz2, f1, f2, W1, W2, W1b, W2b, X);
    gemm_bn1<<<512, 512, 0, stream>>>(X, W1b, b1, Y1, PS, PQ);
    finalize_bn<<<8, 256, 0, stream>>>(PS, PQ, g1, be1, SC1, SH1);
    gemm_bn2<<<512, 512, 0, stream>>>(Y1, W2b, SC1, SH1, b2, Y1, PS, PQ);
    finalize_bn<<<8, 256, 0, stream>>>(PS, PQ, g2, be2, SC2, SH2);
    final_apply<<<(NQ * DH) / (8 * 256), 256, 0, stream>>>(Y1, SC2, SH2, (float*)d_out);
}